// Round 3
// baseline (264.206 us; speedup 1.0000x reference)
//
#include <hip/hip_runtime.h>
#include <math.h>

// mask[i][j] = (j < block_end(i)) && (j != i), where
// block_end(i) = (i / n_nodes + 1) * n_nodes.
// Derivation: ((i>j) | same_block) & (i!=j)  ==  (j < blk_end) & (j != i)
//
// Pure HBM-write-bound: n=8192 -> 268 MB fp32 out, ~0 bytes read.
// Structure: one block per row; 256 threads x 8 float4 nontemporal stores.

typedef float vfloat4 __attribute__((ext_vector_type(4)));  // native vector: OK for nontemporal builtin

__global__ void __launch_bounds__(256)
Create_Mask_23871428231714_kernel(const int* __restrict__ n_nodes_p,
                                  float* __restrict__ out, int n) {
    const int i = blockIdx.x;                       // row
    const int n_nodes = *n_nodes_p;                 // scalar, broadcast
    const int blk_end = (i / n_nodes + 1) * n_nodes;  // row-uniform (one sdiv/block)

    vfloat4* __restrict__ row = reinterpret_cast<vfloat4*>(out + (size_t)i * (size_t)n);
    const int nv = n >> 2;                          // float4s per row (2048)

    for (int v = threadIdx.x; v < nv; v += blockDim.x) {
        const int j0 = v << 2;
        vfloat4 val;
        val.x = ((j0     < blk_end) && (j0     != i)) ? 1.0f : 0.0f;
        val.y = ((j0 + 1 < blk_end) && (j0 + 1 != i)) ? 1.0f : 0.0f;
        val.z = ((j0 + 2 < blk_end) && (j0 + 2 != i)) ? 1.0f : 0.0f;
        val.w = ((j0 + 3 < blk_end) && (j0 + 3 != i)) ? 1.0f : 0.0f;
        __builtin_nontemporal_store(val, row + v);  // global_store_dwordx4 ... nt
    }
}

extern "C" void kernel_launch(void* const* d_in, const int* in_sizes, int n_in,
                              void* d_out, int out_size, void* d_ws, size_t ws_size,
                              hipStream_t stream) {
    (void)in_sizes; (void)n_in; (void)d_ws; (void)ws_size;
    const int* n_nodes_p = (const int*)d_in[0];
    float* out = (float*)d_out;

    // out is n x n -> recover n on host without any device readback
    const int n = (int)llround(sqrt((double)out_size));

    // one block per row; 256 threads, each writes (n/4)/256 float4s (8 for n=8192)
    Create_Mask_23871428231714_kernel<<<dim3(n, 1, 1), dim3(256, 1, 1), 0, stream>>>(
        n_nodes_p, out, n);
}